// Round 10
// baseline (254.594 us; speedup 1.0000x reference)
//
#include <hip/hip_runtime.h>

#define KHOPS  8
#define BS     1024            // block size everywhere
#define MAXL   50176           // max links (LDS tables sized for this)
#define HWORDS (MAXL / 2)      // 25088 u32 words = 100352 B (u16-pair histogram)
#define GRID   256             // scatter/finale grid: 1 block/CU
#define NXCD   8               // merge groups == XCD count
#define RPQ    (GRID / NXCD)   // replicas per merge group = 32
#define TSCALE  2048.0f        // traffic deposit fixed-point scale (Q11)
#define XSCALE  131072.0f      // X_l fixed-point scale (Q17; X < 0.5 guaranteed)

typedef unsigned char  u8;
typedef unsigned short u16;
typedef unsigned int   u32;

// ---------------------------------------------------------------------------
// deposit helper: packed u16-pair histogram, ds_add_u32
// ---------------------------------------------------------------------------
__device__ __forceinline__ void deposit(u32* h, u32 link, float t) {
    atomicAdd(&h[link >> 1], __float2uint_rn(t * TSCALE) << ((link & 1) << 4));
}

// ---------------------------------------------------------------------------
// scatter, iteration 1 (fused convert): reads raw int edges + P, converts to
// packed u16 (writes e16 for later passes) and compact A; bp == 0.5 constant.
// ---------------------------------------------------------------------------
__global__ __launch_bounds__(BS) void scatter_first(
        const float* __restrict__ P,         // (n_paths,3)
        const int*   __restrict__ pl_edges,  // (KHOPS,n_paths)
        u16*   __restrict__ e16,             // out: packed link ids
        float* __restrict__ A,               // out: compact traffic source
        u32*   __restrict__ Trep,            // [GRID][nwords]
        int n_paths, int nwords) {
    __shared__ u32 h[HWORDS];
    const int tid = threadIdx.x;
    const int nthreads = gridDim.x * BS;

    for (int i = tid; i < HWORDS; i += BS) h[i] = 0u;
    __syncthreads();

    for (int p = (blockIdx.x * BS + tid) * 4; p < n_paths; p += 4 * nthreads) {
        uint2 ep[KHOPS];
#pragma unroll
        for (int k = 0; k < KHOPS; ++k) {
            int4 e4 = *(const int4*)&pl_edges[k * n_paths + p];   // coalesced
            ep[k].x = (u32)(e4.x - n_paths) | ((u32)(e4.y - n_paths) << 16);
            ep[k].y = (u32)(e4.z - n_paths) | ((u32)(e4.w - n_paths) << 16);
            *(uint2*)&e16[k * n_paths + p] = ep[k];               // coalesced
        }
        float4 q0 = *(const float4*)&P[3 * p];       // A = P[:,1]
        float4 q1 = *(const float4*)&P[3 * p + 4];
        float4 q2 = *(const float4*)&P[3 * p + 8];
        float t0 = q0.y, t1 = q1.x, t2 = q1.w, t3 = q2.z;
        *(float4*)&A[p] = make_float4(t0, t1, t2, t3);
#pragma unroll
        for (int k = 0; k < KHOPS; ++k) {
            deposit(h, ep[k].x & 0xffffu, t0);
            deposit(h, ep[k].x >> 16,     t1);
            deposit(h, ep[k].y & 0xffffu, t2);
            deposit(h, ep[k].y >> 16,     t3);
            t0 *= 0.5f; t1 *= 0.5f; t2 *= 0.5f; t3 *= 0.5f;
        }
    }
    __syncthreads();

    u32* Tmine = Trep + (size_t)blockIdx.x * nwords;
    for (int i = tid; i < nwords; i += BS) Tmine[i] = h[i];
}

// ---------------------------------------------------------------------------
// scatter, iterations 2+: NO separate link_update kernel — each block
// redundantly computes the (deterministic) bp table from the 8 integer
// partials (coalesced L2-resident reads + poly) straight into LDS as u8 Q8.
// Then the usual full-histogram deposit pass and private-replica flush.
// ---------------------------------------------------------------------------
__global__ __launch_bounds__(BS) void scatter_rest(
        const float* __restrict__ A,
        const u16*   __restrict__ e16,
        const float* __restrict__ Lcap,      // (n_links,1)
        const u32*   __restrict__ partial,   // [NXCD][n_links]
        u32*         __restrict__ Trep,
        int n_paths, int n_links, int nwords) {
    __shared__ u8  bpl[MAXL];                // 50176 B
    __shared__ u32 h[HWORDS];                // 100352 B
    const int tid = threadIdx.x;
    const int nthreads = gridDim.x * BS;

    // ---- fused link update: bp from partials (identical in every block) ----
    for (int l = tid; l < n_links; l += BS) {
        u32 s = 0;
#pragma unroll
        for (int q = 0; q < NXCD; ++q)
            s += partial[(size_t)q * n_links + l];   // coalesced, L2-resident
        float T   = (float)s * (1.0f / TSCALE);
        float cap = Lcap[l] * (1.0f / 1000.0f);
        float rho = T / cap;
        float r2 = rho * rho, r4 = r2 * r2, r8 = r4 * r4, r16 = r8 * r8;
        float r32 = r16 * r16, r33 = r32 * rho;
        float bp = (1.0f - rho) * r32 / (1.0f - r33 + 1e-8f);
        u32 b = __float2uint_rn(bp * 256.0f);
        bpl[l] = (u8)(b > 255u ? 255u : b);
    }
    for (int i = tid; i < HWORDS; i += BS) h[i] = 0u;
    __syncthreads();

    for (int p = (blockIdx.x * BS + tid) * 4; p < n_paths; p += 4 * nthreads) {
        uint2 ep[KHOPS];
#pragma unroll
        for (int k = 0; k < KHOPS; ++k)
            ep[k] = *(const uint2*)&e16[k * n_paths + p];
        float4 a = *(const float4*)&A[p];
        float t0 = a.x, t1 = a.y, t2 = a.z, t3 = a.w;
#pragma unroll
        for (int k = 0; k < KHOPS; ++k) {
            u32 l0 = ep[k].x & 0xffffu, l1 = ep[k].x >> 16;
            u32 l2 = ep[k].y & 0xffffu, l3 = ep[k].y >> 16;
            deposit(h, l0, t0);
            deposit(h, l1, t1);
            deposit(h, l2, t2);
            deposit(h, l3, t3);
            t0 *= (float)(256 - (int)bpl[l0]) * (1.0f / 256.0f);
            t1 *= (float)(256 - (int)bpl[l1]) * (1.0f / 256.0f);
            t2 *= (float)(256 - (int)bpl[l2]) * (1.0f / 256.0f);
            t3 *= (float)(256 - (int)bpl[l3]) * (1.0f / 256.0f);
        }
    }
    __syncthreads();

    u32* Tmine = Trep + (size_t)blockIdx.x * nwords;
    for (int i = tid; i < nwords; i += BS) Tmine[i] = h[i];
}

// ---------------------------------------------------------------------------
// merge: group q sums replicas r == q (mod 8). Replica r was written by
// scatter block r (XCD r%8, round-robin heuristic); merge block has
// q = blockIdx.x & 7 -> same XCD -> L2-local reads.
// ---------------------------------------------------------------------------
__global__ __launch_bounds__(BS) void merge_kernel(
        const u32* __restrict__ Trep,
        u32* __restrict__ partial,           // [NXCD][n_links]
        int n_links, int nwords) {
    const int q = blockIdx.x & (NXCD - 1);
    const int w = (blockIdx.x >> 3) * BS + threadIdx.x;
    if (w >= nwords) return;
    u32 slo = 0, shi = 0;
#pragma unroll 4
    for (int j = 0; j < RPQ; ++j) {
        u32 v = Trep[(size_t)(q + NXCD * j) * nwords + w];
        slo += v & 0xffffu;
        shi += v >> 16;
    }
    *(uint2*)&partial[(size_t)q * n_links + 2 * w] = make_uint2(slo, shi);
}

// ---------------------------------------------------------------------------
// finale: fused link-update + epilogue + gather. Each block redundantly
// computes rho/Lq/pi0 from the 8 partials for ALL links, stores X_l (Q17)
// into LDS, writes its own slice of out_links, then gathers res.
// ---------------------------------------------------------------------------
__global__ __launch_bounds__(BS) void finale_kernel(
        const float* __restrict__ Lcap,
        const u32*   __restrict__ partial,
        const u16*   __restrict__ e16,
        float* __restrict__ res,             // (n_paths,)
        float* __restrict__ out_links,       // (n_links,3)
        int n_paths, int n_links) {
    __shared__ u16 xl[MAXL];
    const int tid = threadIdx.x;
    const int per = (n_links + (int)gridDim.x - 1) / (int)gridDim.x;
    const int lo  = blockIdx.x * per;
    const int hi  = (lo + per < n_links) ? lo + per : n_links;

    for (int l = tid; l < n_links; l += BS) {
        u32 s = 0;
#pragma unroll
        for (int q = 0; q < NXCD; ++q)
            s += partial[(size_t)q * n_links + l];
        float T   = (float)s * (1.0f / TSCALE);
        float cap = Lcap[l] * (1.0f / 1000.0f);
        float rho = T / cap;
        float r2 = rho * rho, r4 = r2 * r2, r8 = r4 * r4, r16 = r8 * r8;
        float r32 = r16 * r16, r33 = r32 * rho;
        float pi0 = (1.0f - rho) / (1.0f - r33);     // no epsilon (ref)
        float S = 1.0f, rp = 1.0f;
#pragma unroll
        for (int m = 1; m <= 32; ++m) { rp *= rho; S += (float)m * rp; }
        float Lq = pi0 * S * (1.0f / 32.0f);
        float X  = Lq * 32000.0f / Lcap[l];
        u32 xf = __float2uint_rn(X * XSCALE);
        xl[l] = (u16)(xf > 65535u ? 65535u : xf);
        if (l >= lo && l < hi) {                     // this block's slice
            out_links[3 * l + 0] = Lq;
            out_links[3 * l + 1] = rho;
            out_links[3 * l + 2] = pi0 * r32;
        }
    }
    __syncthreads();

    const int nthreads = gridDim.x * BS;
    for (int p = (blockIdx.x * BS + tid) * 4; p < n_paths; p += 4 * nthreads) {
        u32 s0 = 0, s1 = 0, s2 = 0, s3 = 0;
#pragma unroll
        for (int k = 0; k < KHOPS; ++k) {
            uint2 ep = *(const uint2*)&e16[k * n_paths + p];
            s0 += xl[ep.x & 0xffffu];
            s1 += xl[ep.x >> 16];
            s2 += xl[ep.y & 0xffffu];
            s3 += xl[ep.y >> 16];
        }
        *(float4*)&res[p] = make_float4((float)s0 * (1.0f / XSCALE),
                                        (float)s1 * (1.0f / XSCALE),
                                        (float)s2 * (1.0f / XSCALE),
                                        (float)s3 * (1.0f / XSCALE));
    }
}

// ---------------------------------------------------------------------------
extern "C" void kernel_launch(void* const* d_in, const int* in_sizes, int n_in,
                              void* d_out, int out_size, void* d_ws, size_t ws_size,
                              hipStream_t stream) {
    const float* P        = (const float*)d_in[0];   // (n_paths, 3)
    const float* Lcap     = (const float*)d_in[1];   // (n_links, 1)
    const int*   pl_edges = (const int*)d_in[3];     // (KHOPS, n_paths)

    const int n_paths = in_sizes[0] / 3;
    const int n_links = in_sizes[1];
    const int n_edges = KHOPS * n_paths;
    const int nwords  = (n_links + 1) / 2;

    // ws layout: e16 | A | partial (u32 NXCD*nl) | Trep (u32 GRID*nwords)
    char* w = (char*)d_ws;
    u16*   e16 = (u16*)w;                     w += (size_t)n_edges * 2;
    w = (char*)(((size_t)w + 15) & ~15ull);
    float* A   = (float*)w;                   w += (size_t)n_paths * 4;
    u32* partial = (u32*)w;                   w += (size_t)NXCD * n_links * 4;
    u32* Trep    = (u32*)w;                   // GRID*nwords*4 = 25.6 MB

    float* res       = (float*)d_out;                // (n_paths,)
    float* out_links = res + n_paths;                // (n_links, 3)

    const int gm = NXCD * ((nwords + BS - 1) / BS);  // XCD-aligned merge grid

    for (int it = 0; it < 3; ++it) {
        if (it == 0)
            scatter_first<<<GRID, BS, 0, stream>>>(P, pl_edges, e16, A, Trep,
                                                   n_paths, nwords);
        else
            scatter_rest<<<GRID, BS, 0, stream>>>(A, e16, Lcap, partial, Trep,
                                                  n_paths, n_links, nwords);
        merge_kernel<<<gm, BS, 0, stream>>>(Trep, partial, n_links, nwords);
    }
    finale_kernel<<<GRID, BS, 0, stream>>>(Lcap, partial, e16, res, out_links,
                                           n_paths, n_links);
}

// Round 11
// 174.208 us; speedup vs baseline: 1.4614x; 1.4614x over previous
//
#include <hip/hip_runtime.h>

#define KHOPS  8
#define BS     1024            // scatter/gather block size
#define MAXL   50176           // max links (LDS tables sized for this)
#define HWORDS (MAXL / 2)      // 25088 u32 words = 100352 B (u16-pair histogram)
#define GRID   256             // scatter/gather grid: 1 block/CU
#define MLW    64              // merge_lu: words per block
#define TSCALE  2048.0f        // traffic deposit fixed-point scale (Q11)
#define XSCALE  131072.0f      // X_l fixed-point scale (Q17; X < 0.5 guaranteed)

typedef unsigned char  u8;
typedef unsigned short u16;
typedef unsigned int   u32;

// ---------------------------------------------------------------------------
// deposit helper: packed u16-pair histogram, ds_add_u32
// ---------------------------------------------------------------------------
__device__ __forceinline__ void deposit(u32* h, u32 link, float t) {
    atomicAdd(&h[link >> 1], __float2uint_rn(t * TSCALE) << ((link & 1) << 4));
}

// ---------------------------------------------------------------------------
// scatter, iteration 1 (fused convert): reads raw int edges + P, converts to
// packed u16 (writes e16 for later passes) and compact A; bp == 0.5 constant.
// ---------------------------------------------------------------------------
__global__ __launch_bounds__(BS) void scatter_first(
        const float* __restrict__ P,         // (n_paths,3)
        const int*   __restrict__ pl_edges,  // (KHOPS,n_paths)
        u16*   __restrict__ e16,             // out: packed link ids
        float* __restrict__ A,               // out: compact traffic source
        u32*   __restrict__ Trep,            // [GRID][nwords]
        int n_paths, int nwords) {
    __shared__ u32 h[HWORDS];
    const int tid = threadIdx.x;
    const int nthreads = gridDim.x * BS;

    for (int i = tid; i < HWORDS; i += BS) h[i] = 0u;
    __syncthreads();

    for (int p = (blockIdx.x * BS + tid) * 4; p < n_paths; p += 4 * nthreads) {
        uint2 ep[KHOPS];
#pragma unroll
        for (int k = 0; k < KHOPS; ++k) {
            int4 e4 = *(const int4*)&pl_edges[k * n_paths + p];   // coalesced
            ep[k].x = (u32)(e4.x - n_paths) | ((u32)(e4.y - n_paths) << 16);
            ep[k].y = (u32)(e4.z - n_paths) | ((u32)(e4.w - n_paths) << 16);
            *(uint2*)&e16[k * n_paths + p] = ep[k];               // coalesced
        }
        float4 q0 = *(const float4*)&P[3 * p];       // A = P[:,1]
        float4 q1 = *(const float4*)&P[3 * p + 4];
        float4 q2 = *(const float4*)&P[3 * p + 8];
        float t0 = q0.y, t1 = q1.x, t2 = q1.w, t3 = q2.z;
        *(float4*)&A[p] = make_float4(t0, t1, t2, t3);
#pragma unroll
        for (int k = 0; k < KHOPS; ++k) {
            deposit(h, ep[k].x & 0xffffu, t0);
            deposit(h, ep[k].x >> 16,     t1);
            deposit(h, ep[k].y & 0xffffu, t2);
            deposit(h, ep[k].y >> 16,     t3);
            t0 *= 0.5f; t1 *= 0.5f; t2 *= 0.5f; t3 *= 0.5f;
        }
    }
    __syncthreads();

    u32* Tmine = Trep + (size_t)blockIdx.x * nwords;
    for (int i = tid; i < nwords; i += BS) Tmine[i] = h[i];
}

// ---------------------------------------------------------------------------
// scatter, iterations 2+: bp table (u8 Q8, precomputed by merge_lu) loaded
// once to LDS (50 KB) + full histogram (100 KB) = 147 KB, 1 block/CU.
// ---------------------------------------------------------------------------
__global__ __launch_bounds__(BS) void scatter_rest(
        const float* __restrict__ A,
        const u16*   __restrict__ e16,
        const u8*    __restrict__ bpq,       // (n_links) Q8
        u32*         __restrict__ Trep,
        int n_paths, int n_links, int nwords) {
    __shared__ u8  bpl[MAXL];                // 50176 B
    __shared__ u32 h[HWORDS];                // 100352 B
    const int tid = threadIdx.x;
    const int nthreads = gridDim.x * BS;

    for (int i = tid; i < n_links; i += BS) bpl[i] = bpq[i];
    for (int i = tid; i < HWORDS; i += BS) h[i] = 0u;
    __syncthreads();

    for (int p = (blockIdx.x * BS + tid) * 4; p < n_paths; p += 4 * nthreads) {
        uint2 ep[KHOPS];
#pragma unroll
        for (int k = 0; k < KHOPS; ++k)
            ep[k] = *(const uint2*)&e16[k * n_paths + p];
        float4 a = *(const float4*)&A[p];
        float t0 = a.x, t1 = a.y, t2 = a.z, t3 = a.w;
#pragma unroll
        for (int k = 0; k < KHOPS; ++k) {
            u32 l0 = ep[k].x & 0xffffu, l1 = ep[k].x >> 16;
            u32 l2 = ep[k].y & 0xffffu, l3 = ep[k].y >> 16;
            deposit(h, l0, t0);
            deposit(h, l1, t1);
            deposit(h, l2, t2);
            deposit(h, l3, t3);
            t0 *= (float)(256 - (int)bpl[l0]) * (1.0f / 256.0f);
            t1 *= (float)(256 - (int)bpl[l1]) * (1.0f / 256.0f);
            t2 *= (float)(256 - (int)bpl[l2]) * (1.0f / 256.0f);
            t3 *= (float)(256 - (int)bpl[l3]) * (1.0f / 256.0f);
        }
    }
    __syncthreads();

    u32* Tmine = Trep + (size_t)blockIdx.x * nwords;
    for (int i = tid; i < nwords; i += BS) Tmine[i] = h[i];
}

// ---------------------------------------------------------------------------
// merge_lu: single-pass 256-replica reduction + link update, no redundancy.
// Block = 64 words x 16 r-groups (1024 thr). Thread (rg,wl) sums replicas
// rg*16..rg*16+15 for word wbase+wl (coalesced 256B rows, 16-deep MLP);
// LDS reduce 16 groups; threads 0..127 do the link update for the block's
// 128 links: bp (Q8 u8) on early iters, full epilogue (+xq) on the last.
// ---------------------------------------------------------------------------
__global__ __launch_bounds__(BS) void merge_lu_kernel(
        const u32*   __restrict__ Trep,      // [GRID][nwords]
        const float* __restrict__ Lcap,      // (n_links,1)
        u8*          __restrict__ bpq,       // out (early iters)
        u16*         __restrict__ xq,        // out (last iter)
        float*       __restrict__ out_links, // out (last iter) (n_links,3)
        int n_links, int nwords, int last) {
    __shared__ u32 red[16][2 * MLW];         // [rgroup][2*wl + lo/hi] = 8 KB
    const int t  = threadIdx.x;
    const int wl = t & (MLW - 1);
    const int rg = t >> 6;                   // wave-uniform (64 lanes per rg)
    const int wbase = blockIdx.x * MLW;
    const int w  = wbase + wl;

    u32 lo = 0, hi = 0;
    if (w < nwords) {
#pragma unroll
        for (int j = 0; j < 16; ++j) {       // 16 independent coalesced loads
            u32 v = Trep[(size_t)(rg * 16 + j) * nwords + w];
            lo += v & 0xffffu;
            hi += v >> 16;
        }
    }
    red[rg][2 * wl]     = lo;
    red[rg][2 * wl + 1] = hi;
    __syncthreads();

    if (t < 2 * MLW) {                       // link l = 2*wbase + t
        const int l = 2 * wbase + t;
        if (l < n_links) {
            u32 s = 0;
#pragma unroll
            for (int j = 0; j < 16; ++j)
                s += red[j][t];              // consecutive t -> conflict-free
            float T   = (float)s * (1.0f / TSCALE);
            float cap = Lcap[l] * (1.0f / 1000.0f);
            float rho = T / cap;
            float r2 = rho * rho, r4 = r2 * r2, r8 = r4 * r4, r16 = r8 * r8;
            float r32 = r16 * r16, r33 = r32 * rho;
            if (!last) {
                float bp = (1.0f - rho) * r32 / (1.0f - r33 + 1e-8f);
                u32 b = __float2uint_rn(bp * 256.0f);
                bpq[l] = (u8)(b > 255u ? 255u : b);
            } else {
                float pi0 = (1.0f - rho) / (1.0f - r33);   // no epsilon (ref)
                float S = 1.0f, rp = 1.0f;
#pragma unroll
                for (int m = 1; m <= 32; ++m) { rp *= rho; S += (float)m * rp; }
                float Lq = pi0 * S * (1.0f / 32.0f);
                float X  = Lq * 32000.0f / Lcap[l];
                u32 xf = __float2uint_rn(X * XSCALE);
                xq[l] = (u16)(xf > 65535u ? 65535u : xf);
                out_links[3 * l + 0] = Lq;
                out_links[3 * l + 1] = rho;
                out_links[3 * l + 2] = pi0 * r32;
            }
        }
    }
}

// ---------------------------------------------------------------------------
// gather: X_l table in LDS (Q17 u16); integer per-path sum, 4 paths/thread.
// ---------------------------------------------------------------------------
__global__ __launch_bounds__(BS) void gather_kernel(
        const u16* __restrict__ e16,
        const u16* __restrict__ xq,
        float*     __restrict__ res,
        int n_paths, int n_links) {
    __shared__ u16 xl[MAXL];
    const int tid = threadIdx.x;
    for (int i = tid; i < n_links; i += BS) xl[i] = xq[i];
    __syncthreads();

    const int nthreads = gridDim.x * BS;
    for (int p = (blockIdx.x * BS + tid) * 4; p < n_paths; p += 4 * nthreads) {
        u32 s0 = 0, s1 = 0, s2 = 0, s3 = 0;
#pragma unroll
        for (int k = 0; k < KHOPS; ++k) {
            uint2 ep = *(const uint2*)&e16[k * n_paths + p];
            s0 += xl[ep.x & 0xffffu];
            s1 += xl[ep.x >> 16];
            s2 += xl[ep.y & 0xffffu];
            s3 += xl[ep.y >> 16];
        }
        *(float4*)&res[p] = make_float4((float)s0 * (1.0f / XSCALE),
                                        (float)s1 * (1.0f / XSCALE),
                                        (float)s2 * (1.0f / XSCALE),
                                        (float)s3 * (1.0f / XSCALE));
    }
}

// ---------------------------------------------------------------------------
extern "C" void kernel_launch(void* const* d_in, const int* in_sizes, int n_in,
                              void* d_out, int out_size, void* d_ws, size_t ws_size,
                              hipStream_t stream) {
    const float* P        = (const float*)d_in[0];   // (n_paths, 3)
    const float* Lcap     = (const float*)d_in[1];   // (n_links, 1)
    const int*   pl_edges = (const int*)d_in[3];     // (KHOPS, n_paths)

    const int n_paths = in_sizes[0] / 3;
    const int n_links = in_sizes[1];
    const int n_edges = KHOPS * n_paths;
    const int nwords  = (n_links + 1) / 2;

    // ws layout: e16 | A | bpq(u8) | xq(u16) | Trep (u32 GRID*nwords)
    char* w = (char*)d_ws;
    u16*   e16 = (u16*)w;                     w += (size_t)n_edges * 2;
    w = (char*)(((size_t)w + 15) & ~15ull);
    float* A   = (float*)w;                   w += (size_t)n_paths * 4;
    u8*    bpq = (u8*)w;                      w += (size_t)n_links;
    w = (char*)(((size_t)w + 15) & ~15ull);
    u16*   xq  = (u16*)w;                     w += (size_t)n_links * 2;
    w = (char*)(((size_t)w + 15) & ~15ull);
    u32* Trep  = (u32*)w;                     // GRID*nwords*4 = 25.6 MB

    float* res       = (float*)d_out;                // (n_paths,)
    float* out_links = res + n_paths;                // (n_links, 3)

    const int gml = (nwords + MLW - 1) / MLW;        // merge_lu grid

    for (int it = 0; it < 3; ++it) {
        if (it == 0)
            scatter_first<<<GRID, BS, 0, stream>>>(P, pl_edges, e16, A, Trep,
                                                   n_paths, nwords);
        else
            scatter_rest<<<GRID, BS, 0, stream>>>(A, e16, bpq, Trep,
                                                  n_paths, n_links, nwords);
        merge_lu_kernel<<<gml, BS, 0, stream>>>(Trep, Lcap, bpq, xq, out_links,
                                                n_links, nwords,
                                                it == 2 ? 1 : 0);
    }
    gather_kernel<<<GRID, BS, 0, stream>>>(e16, xq, res, n_paths, n_links);
}